// Round 3
// baseline (741.810 us; speedup 1.0000x reference)
//
#include <hip/hip_runtime.h>

#define C_CH 16
#define Hdim 128
#define Wdim 128
#define HWdim 16384
#define CHW (C_CH * HWdim)                 // 262144 floats: one [C][H][W] slab
#define PAIR_ELEMS (Bdim * CHW)            // 524288
#define Bdim 2

__device__ __forceinline__ void gadd(float* p, float v) {
  __hip_atomic_fetch_add(p, v, __ATOMIC_RELAXED, __HIP_MEMORY_SCOPE_AGENT);
}

// ---------------------------------------------------------------------------
// Prep: memT[d][m] = mem * temp/sqrt(D)   (sim conv weights, m-contiguous)
//       memR[m][u][v][c]                  (kernel-flipped, c-contiguous)
// ---------------------------------------------------------------------------
struct PrepDesc {
  const float* mem;
  const float* temp;
  float* memT;
  float* memR;
  int M, D, P;
};
struct PrepArgs { PrepDesc d[6]; };

__global__ __launch_bounds__(256) void k_prep(PrepArgs a) {
  PrepDesc de = a.d[blockIdx.y];
  int n = de.M * de.D;
  int idx = blockIdx.x * 256 + threadIdx.x;
  if (idx >= n) return;
  int m = idx / de.D;
  int d = idx - m * de.D;
  float v = de.mem[idx];
  float sc = de.temp[0] / sqrtf((float)de.D);
  de.memT[d * de.M + m] = v * sc;
  int pp = de.P * de.P;
  int c = d / pp;
  int r = d - c * pp;
  int i = r / de.P;
  int j = r - i * de.P;
  de.memR[((m * de.P + (de.P - 1 - i)) * de.P + (de.P - 1 - j)) * C_CH + c] = v;
}

// ---------------------------------------------------------------------------
// Sim conv + per-pixel softmax -> att[m][y][x]  (one batch per dispatch).
// 8x8 tile / block, 512 threads; 8 waves split M. z = scale*2 + (bg?0:1).
// ---------------------------------------------------------------------------
template<int P, int M, int MC>
__device__ __forceinline__ void sim_core(
    const float* __restrict__ xt, float* __restrict__ red,
    const float* __restrict__ memT, float* __restrict__ att,
    int wv, int lane, int x0, int y0)
{
  constexpr int TH = 8 + P - 1, SR = TH + 1;
  const int px = lane & 7, py = lane >> 3;
  const int m0 = wv * MC;
  float acc[MC];
#pragma unroll
  for (int mm = 0; mm < MC; ++mm) acc[mm] = 0.f;

  for (int c = 0; c < C_CH; ++c) {
#pragma unroll
    for (int i = 0; i < P; ++i) {
#pragma unroll
      for (int j = 0; j < P; ++j) {
        float val = xt[(c * TH + py + i) * SR + (px + j)];
        const float* wr = memT + (size_t)(((c * P + i) * P + j)) * M + m0;
#pragma unroll
        for (int mm = 0; mm < MC; ++mm) acc[mm] = fmaf(val, wr[mm], acc[mm]);
      }
    }
  }

  float pm = acc[0];
#pragma unroll
  for (int mm = 1; mm < MC; ++mm) pm = fmaxf(pm, acc[mm]);
  red[wv * 64 + lane] = pm;
  __syncthreads();
  float gm = red[lane];
#pragma unroll
  for (int w = 1; w < 8; ++w) gm = fmaxf(gm, red[w * 64 + lane]);
  __syncthreads();
  float ps = 0.f;
#pragma unroll
  for (int mm = 0; mm < MC; ++mm) { acc[mm] = __expf(acc[mm] - gm); ps += acc[mm]; }
  red[wv * 64 + lane] = ps;
  __syncthreads();
  float tot = 0.f;
#pragma unroll
  for (int w = 0; w < 8; ++w) tot += red[w * 64 + lane];
  float inv = 1.f / tot;

  const int gy = y0 + py, gx = x0 + px;
#pragma unroll
  for (int mm = 0; mm < MC; ++mm)
    att[(size_t)(m0 + mm) * HWdim + gy * Wdim + gx] = acc[mm] * inv;
}

template<int P>
__device__ __forceinline__ void sim_stage(
    float* __restrict__ xt, const float* __restrict__ x,
    int b, int tid, int x0, int y0)
{
  constexpr int PAD = P / 2, TH = 8 + P - 1, SR = TH + 1;
  for (int t = tid; t < C_CH * TH * TH; t += 512) {
    int c = t / (TH * TH);
    int r = t - c * (TH * TH);
    int ly = r / TH, lx = r - ly * TH;
    int gy = y0 - PAD + ly, gx = x0 - PAD + lx;
    float v = 0.f;
    if (gy >= 0 && gy < Hdim && gx >= 0 && gx < Wdim)
      v = x[((b * C_CH + c) * Hdim + gy) * Wdim + gx];
    xt[(c * TH + ly) * SR + lx] = v;
  }
  __syncthreads();
}

struct SimArgs {
  const float* xbg; const float* xtg;
  const float* memTbg[3]; const float* memTtg[3];
  float* att;        // per scale: [72][HW]; first 64 = bg, last 8 = tg
  int b;
};

__global__ __launch_bounds__(512, 8) void k_sim(SimArgs a) {
  __shared__ float xt[C_CH * 14 * 15];   // sized for P=7
  __shared__ float red[8 * 64];

  const int tid = threadIdx.x;
  const int wv = __builtin_amdgcn_readfirstlane(tid >> 6);
  const int lane = tid & 63;
  const int x0 = blockIdx.x * 8, y0 = blockIdx.y * 8;
  const int z = blockIdx.z;
  const int s = z >> 1;          // scale 0,1,2
  const bool isbg = (z & 1) == 0;

  float* attس = a.att + (size_t)s * 72 * HWdim;
  float* att_bg = attس;
  float* att_tg = attس + (size_t)64 * HWdim;

  if (s == 0) {
    sim_stage<3>(xt, isbg ? a.xbg : a.xtg, a.b, tid, x0, y0);
    if (isbg) sim_core<3, 64, 8>(xt, red, a.memTbg[0], att_bg, wv, lane, x0, y0);
    else      sim_core<3, 8, 1>(xt, red, a.memTtg[0], att_tg, wv, lane, x0, y0);
  } else if (s == 1) {
    sim_stage<5>(xt, isbg ? a.xbg : a.xtg, a.b, tid, x0, y0);
    if (isbg) sim_core<5, 64, 8>(xt, red, a.memTbg[1], att_bg, wv, lane, x0, y0);
    else      sim_core<5, 8, 1>(xt, red, a.memTtg[1], att_tg, wv, lane, x0, y0);
  } else {
    sim_stage<7>(xt, isbg ? a.xbg : a.xtg, a.b, tid, x0, y0);
    if (isbg) sim_core<7, 64, 8>(xt, red, a.memTbg[2], att_bg, wv, lane, x0, y0);
    else      sim_core<7, 8, 1>(xt, red, a.memTtg[2], att_tg, wv, lane, x0, y0);
  }
}

// ---------------------------------------------------------------------------
// Read conv (fold of att@mem), invdiv applied, plain stores (no atomics).
// bg: 2 m-chunks of 32 -> separate partial buffers. tg: single chunk of 8.
// z = scale*3 + r; r in {0,1}: bg chunk r; r==2: tg.
// ---------------------------------------------------------------------------
template<int P, int MB, int MC>
__device__ __forceinline__ void read_core(
    float* __restrict__ at, float* __restrict__ S,
    const float* __restrict__ att, const float* __restrict__ memR,
    float* __restrict__ outp, int mbase,
    int tid, int wv, int lane, int x0, int y0)
{
  constexpr int PAD = P / 2, TH = 8 + P - 1, SR = TH + 1;

  for (int t = tid; t < MB * TH * TH; t += 256) {
    int ml = t / (TH * TH);
    int r = t - ml * (TH * TH);
    int ly = r / TH, lx = r - ly * TH;
    int gy = y0 - PAD + ly, gx = x0 - PAD + lx;
    float v = 0.f;
    if (gy >= 0 && gy < Hdim && gx >= 0 && gx < Wdim)
      v = att[(size_t)(mbase + ml) * HWdim + gy * Wdim + gx];
    at[(ml * TH + ly) * SR + lx] = v;
  }
  __syncthreads();

  const int px = lane & 7, py = lane >> 3;
  float acc[C_CH];
#pragma unroll
  for (int c = 0; c < C_CH; ++c) acc[c] = 0.f;

  const int ml0 = wv * MC;
  for (int ml = 0; ml < MC; ++ml) {
    const int m = mbase + ml0 + ml;
    const float* atm = at + (ml0 + ml) * TH * SR;
#pragma unroll
    for (int u = 0; u < P; ++u) {
#pragma unroll
      for (int v2 = 0; v2 < P; ++v2) {
        float val = atm[(py + u) * SR + (px + v2)];
        const float* wr = memR + (size_t)((m * P + u) * P + v2) * C_CH;
#pragma unroll
        for (int c = 0; c < C_CH; ++c) acc[c] = fmaf(val, wr[c], acc[c]);
      }
    }
  }

  // 2-step cross-wave tree into wave 0 (S = [2][64][17])
  if (wv >= 2) {
#pragma unroll
    for (int c = 0; c < C_CH; ++c) S[((wv - 2) * 64 + lane) * 17 + c] = acc[c];
  }
  __syncthreads();
  if (wv < 2) {
#pragma unroll
    for (int c = 0; c < C_CH; ++c) acc[c] += S[(wv * 64 + lane) * 17 + c];
  }
  __syncthreads();
  if (wv == 1) {
#pragma unroll
    for (int c = 0; c < C_CH; ++c) S[lane * 17 + c] = acc[c];
  }
  __syncthreads();
  if (wv == 0) {
    const int gy = y0 + py, gx = x0 + px;
    int cy = min(P - 1, gy + PAD) - max(0, gy + PAD - (Hdim - 1)) + 1;
    int cx = min(P - 1, gx + PAD) - max(0, gx + PAD - (Wdim - 1)) + 1;
    float inv = 1.f / ((float)(cy * cx) + 1e-8f);
#pragma unroll
    for (int c = 0; c < C_CH; ++c) {
      float v = (acc[c] + S[lane * 17 + c]) * inv;
      outp[(size_t)c * HWdim + gy * Wdim + gx] = v;
    }
  }
}

struct ReadArgs {
  const float* att;                  // per scale: [72][HW]
  const float* memRbg[3]; const float* memRtg[3];
  float* pbg;   // [3][2][2][CHW]  (scale, chunk, batch)
  float* ftg;   // [3][2][CHW]     (scale, batch)
  int b;
};

__global__ __launch_bounds__(256, 4) void k_read(ReadArgs a) {
  __shared__ float at[32 * 14 * 15];   // sized for P=7, MB=32
  __shared__ float S[2 * 64 * 17];

  const int tid = threadIdx.x;
  const int wv = __builtin_amdgcn_readfirstlane(tid >> 6);
  const int lane = tid & 63;
  const int x0 = blockIdx.x * 8, y0 = blockIdx.y * 8;
  const int z = blockIdx.z;
  const int s = z / 3;
  const int r = z - s * 3;

  const float* att_s = a.att + (size_t)s * 72 * HWdim;
  if (r < 2) {
    float* outp = a.pbg + (size_t)((s * 2 + r) * 2 + a.b) * CHW;
    if (s == 0)      read_core<3, 32, 8>(at, S, att_s, a.memRbg[0], outp, r * 32, tid, wv, lane, x0, y0);
    else if (s == 1) read_core<5, 32, 8>(at, S, att_s, a.memRbg[1], outp, r * 32, tid, wv, lane, x0, y0);
    else             read_core<7, 32, 8>(at, S, att_s, a.memRbg[2], outp, r * 32, tid, wv, lane, x0, y0);
  } else {
    const float* att_t = att_s + (size_t)64 * HWdim;
    float* outp = a.ftg + (size_t)(s * 2 + a.b) * CHW;
    if (s == 0)      read_core<3, 8, 2>(at, S, att_t, a.memRtg[0], outp, 0, tid, wv, lane, x0, y0);
    else if (s == 1) read_core<5, 8, 2>(at, S, att_t, a.memRtg[1], outp, 0, tid, wv, lane, x0, y0);
    else             read_core<7, 8, 2>(at, S, att_t, a.memRtg[2], outp, 0, tid, wv, lane, x0, y0);
  }
}

// ---------------------------------------------------------------------------
// Fusion
// ---------------------------------------------------------------------------
__global__ __launch_bounds__(256) void k_pool(const float* __restrict__ pbg,
                                              const float* __restrict__ ftg,
                                              float* __restrict__ pooled)
{
  __shared__ float r[256];
  int bid = blockIdx.x;          // br*32 + b*16 + c
  int chunk = blockIdx.y;        // quarter of HW
  int br = bid >> 5;
  int bc = bid & 31;
  int b = bc >> 4, c = bc & 15;
  size_t off = (size_t)c * HWdim + chunk * 4096;
  float s = 0.f;
  if (br == 0) {
    for (int sc = 0; sc < 3; ++sc)
      for (int ch = 0; ch < 2; ++ch) {
        const float* base = pbg + (size_t)((sc * 2 + ch) * 2 + b) * CHW + off;
        for (int t = threadIdx.x; t < 4096; t += 256) s += base[t];
      }
  } else {
    for (int sc = 0; sc < 3; ++sc) {
      const float* base = ftg + (size_t)(sc * 2 + b) * CHW + off;
      for (int t = threadIdx.x; t < 4096; t += 256) s += base[t];
    }
  }
  r[threadIdx.x] = s;
  __syncthreads();
  for (int off2 = 128; off2 > 0; off2 >>= 1) {
    if ((int)threadIdx.x < off2) r[threadIdx.x] += r[threadIdx.x + off2];
    __syncthreads();
  }
  if (threadIdx.x == 0) gadd(&pooled[bid], r[0] * (1.0f / (float)HWdim));
}

__global__ __launch_bounds__(128) void k_mlp(
    const float* __restrict__ pooled,
    const float* __restrict__ w1b, const float* __restrict__ b1b,
    const float* __restrict__ w2b, const float* __restrict__ b2b,
    const float* __restrict__ w1t, const float* __restrict__ b1t,
    const float* __restrict__ w2t, const float* __restrict__ b2t,
    float* __restrict__ wt)
{
  __shared__ float hdn[Bdim][4];
  __shared__ float lg[Bdim][48];
  int t = threadIdx.x;
  for (int br = 0; br < 2; ++br) {
    const float* w1 = br ? w1t : w1b;
    const float* b1 = br ? b1t : b1b;
    const float* w2 = br ? w2t : w2b;
    const float* b2 = br ? b2t : b2b;
    if (t < 8) {
      int b = t >> 2, h = t & 3;
      float s = b1[h];
      for (int c = 0; c < C_CH; ++c) s += pooled[br * 32 + b * 16 + c] * w1[h * 16 + c];
      hdn[b][h] = fmaxf(s, 0.f);
    }
    __syncthreads();
    if (t < 96) {
      int b = t / 48, j = t - b * 48;
      float s = b2[j];
      for (int h = 0; h < 4; ++h) s += hdn[b][h] * w2[j * 4 + h];
      lg[b][j] = s;
    }
    __syncthreads();
    if (t < 32) {
      int b = t >> 4, c = t & 15;
      float l0 = lg[b][c], l1 = lg[b][16 + c], l2 = lg[b][32 + c];
      float m = fmaxf(l0, fmaxf(l1, l2));
      float e0 = __expf(l0 - m), e1 = __expf(l1 - m), e2 = __expf(l2 - m);
      float inv = 1.f / (e0 + e1 + e2);
      wt[((br * 2 + b) * 3 + 0) * 16 + c] = e0 * inv;
      wt[((br * 2 + b) * 3 + 1) * 16 + c] = e1 * inv;
      wt[((br * 2 + b) * 3 + 2) * 16 + c] = e2 * inv;
    }
    __syncthreads();
  }
}

__global__ __launch_bounds__(256) void k_out(const float* __restrict__ pbg,
                                             const float* __restrict__ ftg,
                                             const float* __restrict__ wt,
                                             float* __restrict__ out)
{
  int idx = blockIdx.x * 256 + threadIdx.x;      // 0 .. 2*PAIR_ELEMS-1
  int br  = idx >> 19;                           // PAIR_ELEMS == 2^19
  int rem = idx & ((1 << 19) - 1);               // [b][c][px]
  int bc  = rem >> 14;
  int b = bc >> 4, c = bc & 15;
  float acc = 0.f;
  if (br == 0) {
#pragma unroll
    for (int s = 0; s < 3; ++s) {
      float v = pbg[(size_t)((s * 2 + 0) * 2) * CHW + rem]
              + pbg[(size_t)((s * 2 + 1) * 2) * CHW + rem];
      acc = fmaf(wt[((b) * 3 + s) * 16 + c], v, acc);
    }
  } else {
#pragma unroll
    for (int s = 0; s < 3; ++s) {
      float v = ftg[(size_t)(s * 2) * CHW + rem];
      acc = fmaf(wt[((2 + b) * 3 + s) * 16 + c], v, acc);
    }
  }
  out[idx] = acc;
}

// ---------------------------------------------------------------------------
extern "C" void kernel_launch(void* const* d_in, const int* in_sizes, int n_in,
                              void* d_out, int out_size, void* d_ws, size_t ws_size,
                              hipStream_t stream)
{
  const float* bg = (const float*)d_in[0];
  const float* tg = (const float*)d_in[1];
  const float* bg_mem[3]  = {(const float*)d_in[2],  (const float*)d_in[6],  (const float*)d_in[10]};
  const float* tg_mem[3]  = {(const float*)d_in[3],  (const float*)d_in[7],  (const float*)d_in[11]};
  const float* bg_temp[3] = {(const float*)d_in[4],  (const float*)d_in[8],  (const float*)d_in[12]};
  const float* tg_temp[3] = {(const float*)d_in[5],  (const float*)d_in[9],  (const float*)d_in[13]};
  const float* bg_fc1_w = (const float*)d_in[14];
  const float* bg_fc1_b = (const float*)d_in[15];
  const float* bg_fc2_w = (const float*)d_in[16];
  const float* bg_fc2_b = (const float*)d_in[17];
  const float* tg_fc1_w = (const float*)d_in[18];
  const float* tg_fc1_b = (const float*)d_in[19];
  const float* tg_fc2_w = (const float*)d_in[20];
  const float* tg_fc2_b = (const float*)d_in[21];

  float* ws     = (float*)d_ws;
  float* att    = ws;                                  // 3*72*16384 = 3,538,944
  float* pbg    = att + (size_t)3 * 72 * HWdim;        // 3*2*2*CHW  = 3,145,728
  float* ftg    = pbg + (size_t)12 * CHW;              // 3*2*CHW    = 1,572,864
  float* pooled = ftg + (size_t)6 * CHW;               // 64
  float* wt     = pooled + 64;                         // 192
  float* memT   = wt + 192;                            // 95,616
  float* memR   = memT + 95616;                        // 95,616

  hipMemsetAsync(pooled, 0, 64 * sizeof(float), stream);

  const int   Ms[6] = {64, 64, 64, 8, 8, 8};
  const int   Ps[6] = {3, 5, 7, 3, 5, 7};
  const float* mems[6]  = {bg_mem[0], bg_mem[1], bg_mem[2], tg_mem[0], tg_mem[1], tg_mem[2]};
  const float* temps[6] = {bg_temp[0], bg_temp[1], bg_temp[2], tg_temp[0], tg_temp[1], tg_temp[2]};
  float* memTs[6]; float* memRs[6];
  PrepArgs pa;
  size_t off = 0;
  for (int k = 0; k < 6; ++k) {
    int D = C_CH * Ps[k] * Ps[k];
    memTs[k] = memT + off;
    memRs[k] = memR + off;
    pa.d[k] = {mems[k], temps[k], memTs[k], memRs[k], Ms[k], D, Ps[k]};
    off += (size_t)Ms[k] * D;
  }
  k_prep<<<dim3(196, 6), 256, 0, stream>>>(pa);

  SimArgs sa;
  sa.xbg = bg; sa.xtg = tg; sa.att = att;
  for (int s = 0; s < 3; ++s) { sa.memTbg[s] = memTs[s]; sa.memTtg[s] = memTs[3 + s]; }
  ReadArgs ra;
  ra.att = att; ra.pbg = pbg; ra.ftg = ftg;
  for (int s = 0; s < 3; ++s) { ra.memRbg[s] = memRs[s]; ra.memRtg[s] = memRs[3 + s]; }

  for (int b = 0; b < Bdim; ++b) {
    sa.b = b;
    k_sim<<<dim3(16, 16, 6), 512, 0, stream>>>(sa);
    ra.b = b;
    k_read<<<dim3(16, 16, 9), 256, 0, stream>>>(ra);
  }

  k_pool<<<dim3(64, 4), 256, 0, stream>>>(pbg, ftg, pooled);
  k_mlp<<<1, 128, 0, stream>>>(pooled, bg_fc1_w, bg_fc1_b, bg_fc2_w, bg_fc2_b,
                               tg_fc1_w, tg_fc1_b, tg_fc2_w, tg_fc2_b, wt);
  k_out<<<(2 * PAIR_ELEMS) / 256, 256, 0, stream>>>(pbg, ftg, wt, (float*)d_out);
}

// Round 4
// 403.764 us; speedup vs baseline: 1.8372x; 1.8372x over previous
//
#include <hip/hip_runtime.h>

#define C_CH 16
#define Hdim 128
#define Wdim 128
#define HWdim 16384
#define CHW (C_CH * HWdim)                 // 262144 floats: one [C][H][W] slab
#define Bdim 2
#define PAIR_ELEMS (Bdim * CHW)            // 524288

__device__ __forceinline__ void gadd(float* p, float v) {
  __hip_atomic_fetch_add(p, v, __ATOMIC_RELAXED, __HIP_MEMORY_SCOPE_AGENT);
}

// ---------------------------------------------------------------------------
// Prep: memT[d][m] = mem * temp/sqrt(D)   (sim conv weights, m-contiguous)
//       memR[m][u][v][c]                  (kernel-flipped, c-contiguous)
// ---------------------------------------------------------------------------
struct PrepDesc {
  const float* mem;
  const float* temp;
  float* memT;
  float* memR;
  int M, D, P;
};
struct PrepArgs { PrepDesc d[6]; };

__global__ __launch_bounds__(256) void k_prep(PrepArgs a) {
  PrepDesc de = a.d[blockIdx.y];
  int n = de.M * de.D;
  int idx = blockIdx.x * 256 + threadIdx.x;
  if (idx >= n) return;
  int m = idx / de.D;
  int d = idx - m * de.D;
  float v = de.mem[idx];
  float sc = de.temp[0] / sqrtf((float)de.D);
  de.memT[d * de.M + m] = v * sc;
  int pp = de.P * de.P;
  int c = d / pp;
  int r = d - c * pp;
  int i = r / de.P;
  int j = r - i * de.P;
  de.memR[((m * de.P + (de.P - 1 - i)) * de.P + (de.P - 1 - j)) * C_CH + c] = v;
}

// ---------------------------------------------------------------------------
// Sim conv + per-pixel softmax -> att  (R2 structure: one dispatch per scale,
// direct args, compile-time everything). 8x8 tile, 512 thr, 8 waves split M.
// z: {bg b0, bg b1, tg b0, tg b1}
// ---------------------------------------------------------------------------
template<int P, int M, int MC>
__device__ __forceinline__ void sim_core(
    const float* __restrict__ xt, float* __restrict__ red,
    const float* __restrict__ memT, float* __restrict__ att,
    int b, int wv, int lane, int x0, int y0)
{
  constexpr int TH = 8 + P - 1, SR = TH + 1;
  const int px = lane & 7, py = lane >> 3;
  const int m0 = wv * MC;
  float acc[MC];
#pragma unroll
  for (int mm = 0; mm < MC; ++mm) acc[mm] = 0.f;

  for (int c = 0; c < C_CH; ++c) {
#pragma unroll
    for (int i = 0; i < P; ++i) {
#pragma unroll
      for (int j = 0; j < P; ++j) {
        float val = xt[(c * TH + py + i) * SR + (px + j)];
        const float* wr = memT + (size_t)(((c * P + i) * P + j)) * M + m0;
#pragma unroll
        for (int mm = 0; mm < MC; ++mm) acc[mm] = fmaf(val, wr[mm], acc[mm]);
      }
    }
  }

  float pm = acc[0];
#pragma unroll
  for (int mm = 1; mm < MC; ++mm) pm = fmaxf(pm, acc[mm]);
  red[wv * 64 + lane] = pm;
  __syncthreads();
  float gm = red[lane];
#pragma unroll
  for (int w = 1; w < 8; ++w) gm = fmaxf(gm, red[w * 64 + lane]);
  __syncthreads();
  float ps = 0.f;
#pragma unroll
  for (int mm = 0; mm < MC; ++mm) { acc[mm] = __expf(acc[mm] - gm); ps += acc[mm]; }
  red[wv * 64 + lane] = ps;
  __syncthreads();
  float tot = 0.f;
#pragma unroll
  for (int w = 0; w < 8; ++w) tot += red[w * 64 + lane];
  float inv = 1.f / tot;

  const int gy = y0 + py, gx = x0 + px;
#pragma unroll
  for (int mm = 0; mm < MC; ++mm)
    att[((size_t)(b * M + m0 + mm)) * HWdim + gy * Wdim + gx] = acc[mm] * inv;
}

template<int P>
__global__ __launch_bounds__(512, 8) void k_sim(
    const float* __restrict__ xbg, const float* __restrict__ xtg,
    const float* __restrict__ memTbg, const float* __restrict__ memTtg,
    float* __restrict__ attbg, float* __restrict__ atttg)
{
  constexpr int PAD = P / 2, TH = 8 + P - 1, SR = TH + 1;
  __shared__ float xt[C_CH * TH * SR];
  __shared__ float red[8 * 64];

  const int tid = threadIdx.x;
  const int wv = __builtin_amdgcn_readfirstlane(tid >> 6);
  const int lane = tid & 63;
  const int x0 = blockIdx.x * 8, y0 = blockIdx.y * 8;
  const int z = blockIdx.z;
  const bool isbg = z < 2;
  const int b = z & 1;
  const float* x = isbg ? xbg : xtg;

  for (int t = tid; t < C_CH * TH * TH; t += 512) {
    int c = t / (TH * TH);
    int r = t - c * (TH * TH);
    int ly = r / TH, lx = r - ly * TH;
    int gy = y0 - PAD + ly, gx = x0 - PAD + lx;
    float v = 0.f;
    if (gy >= 0 && gy < Hdim && gx >= 0 && gx < Wdim)
      v = x[((b * C_CH + c) * Hdim + gy) * Wdim + gx];
    xt[(c * TH + ly) * SR + lx] = v;
  }
  __syncthreads();

  if (isbg) sim_core<P, 64, 8>(xt, red, memTbg, attbg, b, wv, lane, x0, y0);
  else      sim_core<P, 8, 1>(xt, red, memTtg, atttg, b, wv, lane, x0, y0);
}

// ---------------------------------------------------------------------------
// Read conv: 16x16 pixel tile, 1 thread = 1 output pixel, 16-c accumulator in
// registers, NO cross-thread reduction / atomics. bg m split 4x over z into
// partial slabs (overlap-count division folded in); tg direct.
// z: 0..7 -> bg (chunk = z>>1, b = z&1); 8..9 -> tg (b = z-8).
// One shared core loop for bg/tg (I-cache friendly).
// ---------------------------------------------------------------------------
template<int P>
__global__ __launch_bounds__(256, 4) void k_read(
    const float* __restrict__ attbg,   // [2][64][HW]
    const float* __restrict__ atttg,   // [2][8][HW]
    const float* __restrict__ memRbg, const float* __restrict__ memRtg,
    float* __restrict__ pbg,           // [4 chunk][2 b][CHW] (this scale)
    float* __restrict__ ftg)           // [2 b][CHW]          (this scale)
{
  constexpr int PAD = P / 2, TH = 16 + P - 1, SR = TH + 1;
  __shared__ float at[16 * TH * SR];

  const int tid = threadIdx.x;
  const int x0 = blockIdx.x * 16, y0 = blockIdx.y * 16;
  const int z = blockIdx.z;
  const bool isbg = z < 8;
  const int b = isbg ? (z & 1) : (z - 8);
  const int mbase = isbg ? (z >> 1) * 16 : 0;
  const int MB = isbg ? 16 : 8;
  const int M = isbg ? 64 : 8;
  const float* att = isbg ? attbg : atttg;
  const float* memR = isbg ? memRbg : memRtg;
  float* outp = isbg ? (pbg + (size_t)((z >> 1) * 2 + b) * CHW)
                     : (ftg + (size_t)b * CHW);

  // stage MB m-planes (+halo, zero pad); rows of TH consecutive floats
  for (int t = tid; t < MB * TH * TH; t += 256) {
    int ml = t / (TH * TH);
    int r = t - ml * (TH * TH);
    int ly = r / TH, lx = r - ly * TH;
    int gy = y0 - PAD + ly, gx = x0 - PAD + lx;
    float v = 0.f;
    if (gy >= 0 && gy < Hdim && gx >= 0 && gx < Wdim)
      v = att[((size_t)(b * M + mbase + ml)) * HWdim + gy * Wdim + gx];
    at[(ml * TH + ly) * SR + lx] = v;
  }
  __syncthreads();

  const int px = tid & 15, py = tid >> 4;
  float acc[C_CH];
#pragma unroll
  for (int c = 0; c < C_CH; ++c) acc[c] = 0.f;

  for (int ml = 0; ml < MB; ++ml) {
    const float* atm = at + ml * TH * SR;
    const float* wbase = memR + (size_t)((mbase + ml) * P * P) * C_CH;
#pragma unroll
    for (int u = 0; u < P; ++u) {
#pragma unroll
      for (int v2 = 0; v2 < P; ++v2) {
        float val = atm[(py + u) * SR + (px + v2)];
        const float* wr = wbase + (u * P + v2) * C_CH;
#pragma unroll
        for (int c = 0; c < C_CH; ++c) acc[c] = fmaf(val, wr[c], acc[c]);
      }
    }
  }

  const int gy = y0 + py, gx = x0 + px;
  int cy = min(P - 1, gy + PAD) - max(0, gy + PAD - (Hdim - 1)) + 1;
  int cx = min(P - 1, gx + PAD) - max(0, gx + PAD - (Wdim - 1)) + 1;
  float inv = 1.f / ((float)(cy * cx) + 1e-8f);
#pragma unroll
  for (int c = 0; c < C_CH; ++c)
    outp[(size_t)c * HWdim + gy * Wdim + gx] = acc[c] * inv;
}

// ---------------------------------------------------------------------------
// Fusion
// ---------------------------------------------------------------------------
__global__ __launch_bounds__(256) void k_pool(const float* __restrict__ pbg,
                                              const float* __restrict__ ftg,
                                              float* __restrict__ pooled)
{
  __shared__ float r[256];
  int bid = blockIdx.x;          // br*32 + b*16 + c
  int chunk = blockIdx.y;        // quarter of HW
  int br = bid >> 5;
  int bc = bid & 31;
  int b = bc >> 4, c = bc & 15;
  size_t off = (size_t)c * HWdim + chunk * 4096;
  float s = 0.f;
  if (br == 0) {
    for (int sc = 0; sc < 3; ++sc)
      for (int ch = 0; ch < 4; ++ch) {
        const float* base = pbg + (size_t)((sc * 4 + ch) * 2 + b) * CHW + off;
        for (int t = threadIdx.x; t < 4096; t += 256) s += base[t];
      }
  } else {
    for (int sc = 0; sc < 3; ++sc) {
      const float* base = ftg + (size_t)(sc * 2 + b) * CHW + off;
      for (int t = threadIdx.x; t < 4096; t += 256) s += base[t];
    }
  }
  r[threadIdx.x] = s;
  __syncthreads();
  for (int off2 = 128; off2 > 0; off2 >>= 1) {
    if ((int)threadIdx.x < off2) r[threadIdx.x] += r[threadIdx.x + off2];
    __syncthreads();
  }
  if (threadIdx.x == 0) gadd(&pooled[bid], r[0] * (1.0f / (float)HWdim));
}

__global__ __launch_bounds__(128) void k_mlp(
    const float* __restrict__ pooled,
    const float* __restrict__ w1b, const float* __restrict__ b1b,
    const float* __restrict__ w2b, const float* __restrict__ b2b,
    const float* __restrict__ w1t, const float* __restrict__ b1t,
    const float* __restrict__ w2t, const float* __restrict__ b2t,
    float* __restrict__ wt)
{
  __shared__ float hdn[Bdim][4];
  __shared__ float lg[Bdim][48];
  int t = threadIdx.x;
  for (int br = 0; br < 2; ++br) {
    const float* w1 = br ? w1t : w1b;
    const float* b1 = br ? b1t : b1b;
    const float* w2 = br ? w2t : w2b;
    const float* b2 = br ? b2t : b2b;
    if (t < 8) {
      int b = t >> 2, h = t & 3;
      float s = b1[h];
      for (int c = 0; c < C_CH; ++c) s += pooled[br * 32 + b * 16 + c] * w1[h * 16 + c];
      hdn[b][h] = fmaxf(s, 0.f);
    }
    __syncthreads();
    if (t < 96) {
      int b = t / 48, j = t - b * 48;
      float s = b2[j];
      for (int h = 0; h < 4; ++h) s += hdn[b][h] * w2[j * 4 + h];
      lg[b][j] = s;
    }
    __syncthreads();
    if (t < 32) {
      int b = t >> 4, c = t & 15;
      float l0 = lg[b][c], l1 = lg[b][16 + c], l2 = lg[b][32 + c];
      float m = fmaxf(l0, fmaxf(l1, l2));
      float e0 = __expf(l0 - m), e1 = __expf(l1 - m), e2 = __expf(l2 - m);
      float inv = 1.f / (e0 + e1 + e2);
      wt[((br * 2 + b) * 3 + 0) * 16 + c] = e0 * inv;
      wt[((br * 2 + b) * 3 + 1) * 16 + c] = e1 * inv;
      wt[((br * 2 + b) * 3 + 2) * 16 + c] = e2 * inv;
    }
    __syncthreads();
  }
}

__global__ __launch_bounds__(256) void k_out(const float* __restrict__ pbg,
                                             const float* __restrict__ ftg,
                                             const float* __restrict__ wt,
                                             float* __restrict__ out)
{
  int idx = blockIdx.x * 256 + threadIdx.x;      // 0 .. 2*PAIR_ELEMS-1
  int br  = idx >> 19;                           // PAIR_ELEMS == 2^19
  int rem = idx & ((1 << 19) - 1);               // [b][c][HW]
  int b   = rem >> 18;                           // CHW == 2^18
  int off = rem & ((1 << 18) - 1);               // [c][HW]
  int c   = off >> 14;
  float acc = 0.f;
  if (br == 0) {
#pragma unroll
    for (int s = 0; s < 3; ++s) {
      float v = 0.f;
#pragma unroll
      for (int ch = 0; ch < 4; ++ch)
        v += pbg[(size_t)((s * 4 + ch) * 2 + b) * CHW + off];
      acc = fmaf(wt[(b * 3 + s) * 16 + c], v, acc);
    }
  } else {
#pragma unroll
    for (int s = 0; s < 3; ++s) {
      float v = ftg[(size_t)(s * 2 + b) * CHW + off];
      acc = fmaf(wt[((2 + b) * 3 + s) * 16 + c], v, acc);
    }
  }
  out[idx] = acc;
}

// ---------------------------------------------------------------------------
extern "C" void kernel_launch(void* const* d_in, const int* in_sizes, int n_in,
                              void* d_out, int out_size, void* d_ws, size_t ws_size,
                              hipStream_t stream)
{
  const float* bg = (const float*)d_in[0];
  const float* tg = (const float*)d_in[1];
  const float* bg_mem[3]  = {(const float*)d_in[2],  (const float*)d_in[6],  (const float*)d_in[10]};
  const float* tg_mem[3]  = {(const float*)d_in[3],  (const float*)d_in[7],  (const float*)d_in[11]};
  const float* bg_temp[3] = {(const float*)d_in[4],  (const float*)d_in[8],  (const float*)d_in[12]};
  const float* tg_temp[3] = {(const float*)d_in[5],  (const float*)d_in[9],  (const float*)d_in[13]};
  const float* bg_fc1_w = (const float*)d_in[14];
  const float* bg_fc1_b = (const float*)d_in[15];
  const float* bg_fc2_w = (const float*)d_in[16];
  const float* bg_fc2_b = (const float*)d_in[17];
  const float* tg_fc1_w = (const float*)d_in[18];
  const float* tg_fc1_b = (const float*)d_in[19];
  const float* tg_fc2_w = (const float*)d_in[20];
  const float* tg_fc2_b = (const float*)d_in[21];

  float* ws     = (float*)d_ws;
  float* att    = ws;                                  // [2][72][HW] per-scale reuse = 2,359,296
  float* pbg    = att + (size_t)2 * 72 * HWdim;        // [3][4][2][CHW] = 6,291,456
  float* ftg    = pbg + (size_t)24 * CHW;              // [3][2][CHW]    = 1,572,864
  float* pooled = ftg + (size_t)6 * CHW;               // 64
  float* wt     = pooled + 64;                         // 192
  float* memT   = wt + 192;                            // 95,616
  float* memR   = memT + 95616;                        // 95,616

  float* attbg = att;                                  // [2][64][HW]
  float* atttg = att + (size_t)2 * 64 * HWdim;         // [2][8][HW]

  hipMemsetAsync(pooled, 0, 64 * sizeof(float), stream);

  const int   Ms[6] = {64, 64, 64, 8, 8, 8};
  const int   Ps[6] = {3, 5, 7, 3, 5, 7};
  const float* mems[6]  = {bg_mem[0], bg_mem[1], bg_mem[2], tg_mem[0], tg_mem[1], tg_mem[2]};
  const float* temps[6] = {bg_temp[0], bg_temp[1], bg_temp[2], tg_temp[0], tg_temp[1], tg_temp[2]};
  float* memTs[6]; float* memRs[6];
  PrepArgs pa;
  size_t off = 0;
  for (int k = 0; k < 6; ++k) {
    int D = C_CH * Ps[k] * Ps[k];
    memTs[k] = memT + off;
    memRs[k] = memR + off;
    pa.d[k] = {mems[k], temps[k], memTs[k], memRs[k], Ms[k], D, Ps[k]};
    off += (size_t)Ms[k] * D;
  }
  k_prep<<<dim3(196, 6), 256, 0, stream>>>(pa);

  dim3 gs(16, 16, 4), bs(512);
  dim3 gr(8, 8, 10), brd(256);

  k_sim<3><<<gs, bs, 0, stream>>>(bg, tg, memTs[0], memTs[3], attbg, atttg);
  k_read<3><<<gr, brd, 0, stream>>>(attbg, atttg, memRs[0], memRs[3],
                                    pbg + (size_t)0 * 8 * CHW, ftg + (size_t)0 * 2 * CHW);
  k_sim<5><<<gs, bs, 0, stream>>>(bg, tg, memTs[1], memTs[4], attbg, atttg);
  k_read<5><<<gr, brd, 0, stream>>>(attbg, atttg, memRs[1], memRs[4],
                                    pbg + (size_t)1 * 8 * CHW, ftg + (size_t)1 * 2 * CHW);
  k_sim<7><<<gs, bs, 0, stream>>>(bg, tg, memTs[2], memTs[5], attbg, atttg);
  k_read<7><<<gr, brd, 0, stream>>>(attbg, atttg, memRs[2], memRs[5],
                                    pbg + (size_t)2 * 8 * CHW, ftg + (size_t)2 * 2 * CHW);

  k_pool<<<dim3(64, 4), 256, 0, stream>>>(pbg, ftg, pooled);
  k_mlp<<<1, 128, 0, stream>>>(pooled, bg_fc1_w, bg_fc1_b, bg_fc2_w, bg_fc2_b,
                               tg_fc1_w, tg_fc1_b, tg_fc2_w, tg_fc2_b, wt);
  k_out<<<(2 * PAIR_ELEMS) / 256, 256, 0, stream>>>(pbg, ftg, wt, (float*)d_out);
}